// Round 4
// baseline (237.000 us; speedup 1.0000x reference)
//
#include <hip/hip_runtime.h>
#include <hip/hip_bf16.h>
#include <stdint.h>

// ---------------------------------------------------------------------------
// Self-attention, B=4 S=2048 D=1024, fp32 in/out, fp16 MFMA compute.
//   0) cvt: x -> xh fp16; w_q/w_k/w_v -> wh fp16 (one dispatch)
//   1) proj3 (R10): ONE z-merged kernel computes q, k AND vt, sharing the
//      staged A(x) tile across all three weight matrices.
//   2) scores = q_b @ k_b^T -> fp16 (z=batch)   [gemm512, unchanged]
//   3) softmax rows in place fp16->fp16
//   4) out_b = attn_b @ vt_b^T (fp32)           [gemm_out R9, unchanged]
// proj3: BM=128 BN=128 BK=32, 256 thr (4 waves, 64x64 per wave per z),
// acc[3][4][4] = 192 VGPR. Per K-tile per wave: 48 MFMA vs 16 ds_read_b128
// and 8 staged chunks -> 3x arithmetic intensity per barrier vs split-z.
// R9 stage-ahead double-buffer (2x32KB = 64KB -> 2 blocks/CU), single
// __syncthreads per K-tile. Grid (64,8)=512 = 2 balanced rounds at 2/CU.
// LDS swizzle for 64B rows: global k-chunk c XOR ((r>>1)&3) -> 2-way (free).
// Accumulation order per output identical to split-z version -> bit-identical
// numerics (absmax canary 0.02539062).
// ---------------------------------------------------------------------------

typedef __attribute__((ext_vector_type(8))) _Float16 f16x8;
typedef __attribute__((ext_vector_type(4))) float f32x4;
typedef __attribute__((ext_vector_type(4))) unsigned short u16x4;

__device__ inline unsigned short f2h(float f) {
    union { _Float16 h; unsigned short u; } x;
    x.h = (_Float16)f;   // RNE
    return x.u;
}
__device__ inline float h2f(unsigned short u) {
    union { unsigned short u; _Float16 h; } x;
    x.u = u;
    return (float)x.h;
}

__device__ inline void async16(const unsigned short* g, unsigned short* l) {
    __builtin_amdgcn_global_load_lds(
        (__attribute__((address_space(1))) void*)g,
        (__attribute__((address_space(3))) void*)l, 16, 0, 0);
}

// ---------------------------------------------------------------------------
// proj3: x[8192][1024] fp16 @ {wq,wk,wv}^T -> q,k fp16 row-major + vt[b][d][s].
// LDS per 16384-half buffer: A @0, B0 @4096, B1 @8192, B2 @12288 (rows of 32
// halves = 4 chunks of 8; chunk l -> row l>>2, slot l&3 holds global k-chunk
// (l&3)^((r>>1)&3)). K fixed = 1024 -> 32 tiles of BK=32.
// ---------------------------------------------------------------------------
__global__ __launch_bounds__(256, 2)
void proj3(const unsigned short* __restrict__ xh,
           const unsigned short* __restrict__ wh,
           unsigned short* __restrict__ q,
           unsigned short* __restrict__ kk,
           unsigned short* __restrict__ vt)
{
    __shared__ __align__(16) unsigned short smem[2 * 16384];   // 64 KB

    const int tid  = threadIdx.x;
    const int lane = tid & 63;
    const int wave = tid >> 6;          // 0..3
    const int wr   = wave >> 1, wc = wave & 1;
    const int quad = lane >> 4, lrow = lane & 15;
    const int bm   = blockIdx.x, bn = blockIdx.y;   // bm fastest (L2: share W)

    // staging pointers: chunk l = tid + 256*i -> row r = l>>2, LDS slot l*8
    // (linear per wave: base + lane*16B), global k-chunk pre-swizzled.
    const unsigned short* gA[2];
    const unsigned short* gB[2];
#pragma unroll
    for (int i = 0; i < 2; ++i) {
        const int l = tid + 256 * i;
        const int r = l >> 2;
        const int c = (l & 3) ^ ((r >> 1) & 3);
        gA[i] = xh + (long)(bm * 128 + r) * 1024 + c * 8;
        gB[i] = wh + (long)(bn * 128 + r) * 1024 + c * 8;
    }

    f32x4 acc[3][4][4];
#pragma unroll
    for (int z = 0; z < 3; ++z)
#pragma unroll
        for (int m = 0; m < 4; ++m)
#pragma unroll
            for (int n = 0; n < 4; ++n)
                acc[z][m][n] = f32x4{0.f, 0.f, 0.f, 0.f};

    // fragment read column: logical chunk = quad, phys = quad ^ ((row>>1)&3);
    // row = base + lrow with base % 16 == 0 -> swz = (lrow>>1)&3 (lane-const).
    const int pc = (quad ^ ((lrow >> 1) & 3)) * 8;

    // ---- prologue: tile 0 -> buf0 ----
#pragma unroll
    for (int i = 0; i < 2; ++i)
        async16(gA[i], &smem[(tid + 256 * i) * 8]);
#pragma unroll
    for (int z = 0; z < 3; ++z)
#pragma unroll
        for (int i = 0; i < 2; ++i)
            async16(gB[i] + (long)z * 1048576,
                    &smem[4096 * (1 + z) + (tid + 256 * i) * 8]);
#pragma unroll
    for (int i = 0; i < 2; ++i) { gA[i] += 32; gB[i] += 32; }
    __syncthreads();   // implicit vmcnt(0): tile0 visible

    for (int t = 0; t < 32; ++t) {
        const unsigned short* cb = smem + (t & 1) * 16384;

        // stage tile t+1 into the other buffer (dead since barrier t-1);
        // latency hides under this tile's 48 MFMA.
        if (t + 1 < 32) {
            unsigned short* nb = smem + ((t + 1) & 1) * 16384;
#pragma unroll
            for (int i = 0; i < 2; ++i) {
                async16(gA[i], &nb[(tid + 256 * i) * 8]);
                gA[i] += 32;
            }
#pragma unroll
            for (int z = 0; z < 3; ++z)
#pragma unroll
                for (int i = 0; i < 2; ++i)
                    async16(gB[i] + (long)z * 1048576,
                            &nb[4096 * (1 + z) + (tid + 256 * i) * 8]);
#pragma unroll
            for (int i = 0; i < 2; ++i) gB[i] += 32;
        }

        f16x8 af[4];
#pragma unroll
        for (int mt = 0; mt < 4; ++mt)
            af[mt] = *(const f16x8*)&cb[(wr * 64 + mt * 16 + lrow) * 32 + pc];
#pragma unroll
        for (int z = 0; z < 3; ++z) {
            f16x8 bf[4];
#pragma unroll
            for (int nt = 0; nt < 4; ++nt)
                bf[nt] = *(const f16x8*)
                    &cb[4096 * (1 + z) + (wc * 64 + nt * 16 + lrow) * 32 + pc];
#pragma unroll
            for (int mt = 0; mt < 4; ++mt)
#pragma unroll
                for (int nt = 0; nt < 4; ++nt)
                    acc[z][mt][nt] = __builtin_amdgcn_mfma_f32_16x16x32_f16(
                        af[mt], bf[nt], acc[z][mt][nt], 0, 0, 0);
        }

        if (t + 1 < 32)
            __syncthreads();   // drain(t+1 loads) + all waves done with cb
    }

    // ---- epilogue: q, k row-major fp16 ----
#pragma unroll
    for (int z = 0; z < 2; ++z) {
        unsigned short* dst = z ? kk : q;
#pragma unroll
        for (int mt = 0; mt < 4; ++mt)
#pragma unroll
            for (int nt = 0; nt < 4; ++nt)
#pragma unroll
                for (int r = 0; r < 4; ++r) {
                    const int row = bm * 128 + wr * 64 + mt * 16 + quad * 4 + r;
                    const int col = bn * 128 + wc * 64 + nt * 16 + lrow;
                    dst[(long)row * 1024 + col] = f2h(acc[z][mt][nt][r]);
                }
    }

    // ---- epilogue: vt transpose (2 bands of 64 token-rows) ----
    // T[col 128][row 64] pitch 72 halves; aliases smem (dead after loop).
    unsigned short* T = smem;   // 128*72 = 9216 halves <= 32768
#pragma unroll
    for (int p = 0; p < 2; ++p) {
        __syncthreads();
        if (wr == p) {
#pragma unroll
            for (int mt = 0; mt < 4; ++mt)
#pragma unroll
                for (int nt = 0; nt < 4; ++nt) {
                    const int row_l = mt * 16 + quad * 4;
                    const int col_l = wc * 64 + nt * 16 + lrow;
                    u16x4 pk = {f2h(acc[2][mt][nt][0]), f2h(acc[2][mt][nt][1]),
                                f2h(acc[2][mt][nt][2]), f2h(acc[2][mt][nt][3])};
                    *(u16x4*)&T[col_l * 72 + row_l] = pk;
                }
        }
        __syncthreads();
        // copy out: 128 cols x 64 rows = 8192 halves = 256 thr x 32
        const int c  = tid >> 1;
        const int j0 = (tid & 1) * 32;
        const int tok0 = bm * 128 + p * 64;   // 128-row tile never crosses
        const int bb = tok0 >> 11;            // a batch boundary (2048%128=0)
        const int s0 = (tok0 & 2047) + j0;
        unsigned short* dst = vt + (long)bb * 2097152 +
                              (long)(bn * 128 + c) * 2048 + s0;
        const unsigned short* srcT = &T[c * 72 + j0];
        *(f16x8*)dst        = *(const f16x8*)srcT;
        *(f16x8*)(dst + 8)  = *(const f16x8*)(srcT + 8);
        *(f16x8*)(dst + 16) = *(const f16x8*)(srcT + 16);
        *(f16x8*)(dst + 24) = *(const f16x8*)(srcT + 24);
    }
}

// MODE 1: fp16 row-major into C (scores). Tile: BM=256 x BN, BK=64.
// 8 waves: wr=wave>>1 (4), wc=wave&1 (2). Serial stage->drain->compute,
// 48 KB LDS (best measured structure for this K at 2-3 blocks/CU).
template <int MODE, int BN>
__global__ __launch_bounds__(512)
void gemm512(const unsigned short* __restrict__ A,
             const unsigned short* __restrict__ B,
             void* __restrict__ C, void* __restrict__ C2,
             int K, int ldA, int ldB, int ldC,
             long sAz, long sBz, long sCz)
{
    constexpr int NT = BN / 32;           // MFMA col-tiles per wave
    constexpr int BI = BN / 64;           // B staging chunks per thread
    __shared__ __align__(16) unsigned short smem[256 * 64 + BN * 64];
    unsigned short* As = smem;
    unsigned short* Bs = smem + 256 * 64;

    const int tid  = threadIdx.x;
    const int lane = tid & 63;
    const int wave = tid >> 6;
    const int wr   = wave >> 1, wc = wave & 1;
    const int quad = lane >> 4, lrow = lane & 15;
    const int bm   = blockIdx.x, bn = blockIdx.y, z = blockIdx.z;  // bm fastest

    const unsigned short* Az = A + (long)z * sAz;
    const unsigned short* Bz = B + (long)z * sBz;

    const unsigned short* gA[4];
    const unsigned short* gB[BI];
#pragma unroll
    for (int i = 0; i < 4; ++i) {
        const int l = tid + 512 * i;
        const int r = l >> 3;
        const int c = (l & 7) ^ (r & 7);
        gA[i] = Az + (long)(bm * 256 + r) * ldA + c * 8;
    }
#pragma unroll
    for (int i = 0; i < BI; ++i) {
        const int l = tid + 512 * i;
        const int r = l >> 3;
        const int c = (l & 7) ^ (r & 7);
        gB[i] = Bz + (long)(bn * BN + r) * ldB + c * 8;
    }

    f32x4 acc[4][NT];
#pragma unroll
    for (int i = 0; i < 4; ++i)
#pragma unroll
        for (int j = 0; j < NT; ++j)
            acc[i][j] = f32x4{0.f, 0.f, 0.f, 0.f};

    const int fr = lrow & 7;   // row bits for fragment de-swizzle

    for (int k0 = 0; k0 < K; k0 += 64) {
#pragma unroll
        for (int i = 0; i < 4; ++i) async16(gA[i], &As[(tid + 512 * i) * 8]);
#pragma unroll
        for (int i = 0; i < BI; ++i) async16(gB[i], &Bs[(tid + 512 * i) * 8]);
#pragma unroll
        for (int i = 0; i < 4; ++i) gA[i] += 64;
#pragma unroll
        for (int i = 0; i < BI; ++i) gB[i] += 64;
        __syncthreads();   // drains vmcnt -> tiles visible

#pragma unroll
        for (int ks = 0; ks < 2; ++ks) {
            const int pc = (((ks << 2) + quad) ^ fr) * 8;
            f16x8 af[4], bf[NT];
#pragma unroll
            for (int mt = 0; mt < 4; ++mt)
                af[mt] = *(const f16x8*)&As[(wr * 64 + mt * 16 + lrow) * 64 + pc];
#pragma unroll
            for (int nt = 0; nt < NT; ++nt)
                bf[nt] = *(const f16x8*)&Bs[(wc * (BN / 2) + nt * 16 + lrow) * 64 + pc];
#pragma unroll
            for (int mt = 0; mt < 4; ++mt)
#pragma unroll
                for (int nt = 0; nt < NT; ++nt)
                    acc[mt][nt] = __builtin_amdgcn_mfma_f32_16x16x32_f16(
                        af[mt], bf[nt], acc[mt][nt], 0, 0, 0);
        }
        __syncthreads();   // LDS reusable
    }

    const int col_base = bn * BN + wc * (BN / 2);
    const int row_base = bm * 256 + wr * 64;
    const long zC = (long)z * sCz;
#pragma unroll
    for (int mt = 0; mt < 4; ++mt)
#pragma unroll
        for (int nt = 0; nt < NT; ++nt)
#pragma unroll
            for (int r = 0; r < 4; ++r) {
                const int row = row_base + mt * 16 + quad * 4 + r;
                const int col = col_base + nt * 16 + lrow;
                if (MODE == 2)
                    ((float*)C)[zC + (long)row * ldC + col] = acc[mt][nt][r];
                else
                    ((unsigned short*)C)[zC + (long)row * ldC + col] =
                        f2h(acc[mt][nt][r]);
            }
}

// R9 out GEMM. BM=256 x BN=64, BK=64, fp32 row-major C. Double-buffered
// 2-phase: stage(t+1) issued BEFORE compute(t); ONE __syncthreads per K-tile.
// LDS 2 x 40 KB = 80 KB -> 2 blocks/CU (matches 512-block grid).
__global__ __launch_bounds__(512)
void gemm_out(const unsigned short* __restrict__ A,
              const unsigned short* __restrict__ B,
              float* __restrict__ C,
              int K, int ldA, int ldB, int ldC,
              long sAz, long sBz, long sCz)
{
    constexpr int TILE_H = 256 * 64 + 64 * 64;   // 20480 halves = 40 KB
    __shared__ __align__(16) unsigned short smem[2 * TILE_H];

    const int tid  = threadIdx.x;
    const int lane = tid & 63;
    const int wave = tid >> 6;
    const int wr   = wave >> 1, wc = wave & 1;
    const int quad = lane >> 4, lrow = lane & 15;
    const int bm   = blockIdx.x, bn = blockIdx.y, z = blockIdx.z;  // bm fastest

    const unsigned short* Az = A + (long)z * sAz;
    const unsigned short* Bz = B + (long)z * sBz;

    const unsigned short* gA[4];
    const unsigned short* gB1;
#pragma unroll
    for (int i = 0; i < 4; ++i) {
        const int l = tid + 512 * i;
        const int r = l >> 3;
        const int c = (l & 7) ^ (r & 7);
        gA[i] = Az + (long)(bm * 256 + r) * ldA + c * 8;
    }
    {
        const int r = tid >> 3;
        const int c = (tid & 7) ^ (r & 7);
        gB1 = Bz + (long)(bn * 64 + r) * ldB + c * 8;
    }

    f32x4 acc[4][2];
#pragma unroll
    for (int i = 0; i < 4; ++i)
#pragma unroll
        for (int j = 0; j < 2; ++j)
            acc[i][j] = f32x4{0.f, 0.f, 0.f, 0.f};

    const int fr = lrow & 7;
    const int ntiles = K >> 6;

    // prologue: stage tile0 into buf0
#pragma unroll
    for (int i = 0; i < 4; ++i) async16(gA[i], &smem[(tid + 512 * i) * 8]);
    async16(gB1, &smem[256 * 64 + tid * 8]);
#pragma unroll
    for (int i = 0; i < 4; ++i) gA[i] += 64;
    gB1 += 64;
    __syncthreads();   // drains vmcnt(0): tile0 visible

    for (int t = 0; t < ntiles; ++t) {
        const unsigned short* As = smem + (t & 1) * TILE_H;
        const unsigned short* Bs = As + 256 * 64;

        if (t + 1 < ntiles) {
            unsigned short* nA = smem + ((t + 1) & 1) * TILE_H;
#pragma unroll
            for (int i = 0; i < 4; ++i) {
                async16(gA[i], &nA[(tid + 512 * i) * 8]);
                gA[i] += 64;
            }
            async16(gB1, &nA[256 * 64 + tid * 8]);
            gB1 += 64;
        }

#pragma unroll
        for (int ks = 0; ks < 2; ++ks) {
            const int pc = (((ks << 2) + quad) ^ fr) * 8;
            f16x8 af[4], bf[2];
#pragma unroll
            for (int mt = 0; mt < 4; ++mt)
                af[mt] = *(const f16x8*)&As[(wr * 64 + mt * 16 + lrow) * 64 + pc];
#pragma unroll
            for (int nt = 0; nt < 2; ++nt)
                bf[nt] = *(const f16x8*)&Bs[(wc * 32 + nt * 16 + lrow) * 64 + pc];
#pragma unroll
            for (int mt = 0; mt < 4; ++mt)
#pragma unroll
                for (int nt = 0; nt < 2; ++nt)
                    acc[mt][nt] = __builtin_amdgcn_mfma_f32_16x16x32_f16(
                        af[mt], bf[nt], acc[mt][nt], 0, 0, 0);
        }

        if (t + 1 < ntiles)
            __syncthreads();   // drain(t+1 loads) + all waves done reading buf
    }

    const int col_base = bn * 64 + wc * 32;
    const int row_base = bm * 256 + wr * 64;
    const long zC = (long)z * sCz;
#pragma unroll
    for (int mt = 0; mt < 4; ++mt)
#pragma unroll
        for (int nt = 0; nt < 2; ++nt)
#pragma unroll
            for (int r = 0; r < 4; ++r) {
                const int row = row_base + mt * 16 + quad * 4 + r;
                const int col = col_base + nt * 16 + lrow;
                C[zC + (long)row * ldC + col] = acc[mt][nt][r];
            }
}

// fused fp32 -> fp16 conversion: blocks [0,4096) -> x, [4096,5632) -> weights
__global__ __launch_bounds__(256)
void cvt_all(const float* __restrict__ x, const float* __restrict__ w0,
             const float* __restrict__ w1, const float* __restrict__ w2,
             unsigned short* __restrict__ xh, unsigned short* __restrict__ wh)
{
    const int bid = blockIdx.x;
    const float* s;
    unsigned short* d;
    long i;
    if (bid < 4096) {
        s = x; d = xh;
        i = ((long)bid * 256 + threadIdx.x) * 8;
    } else {
        const int wid = bid - 4096;          // [0,1536)
        const int w = wid >> 9;              // weight index
        s = (w == 0) ? w0 : (w == 1) ? w1 : w2;
        d = wh + (long)w * 1048576;
        i = ((long)(wid & 511) * 256 + threadIdx.x) * 8;
    }
    f32x4 a = *(const f32x4*)(s + i);
    f32x4 b = *(const f32x4*)(s + i + 4);
    union { unsigned short u[8]; f16x8 v; } t;
#pragma unroll
    for (int j = 0; j < 4; ++j) { t.u[j] = f2h(a[j]); t.u[4 + j] = f2h(b[j]); }
    *(f16x8*)(d + i) = t.v;
}

// in-place fp16 row softmax: row = 2048 fp16, one block per row.
__global__ __launch_bounds__(256)
void softmax16(unsigned short* __restrict__ sc)
{
    const long row = blockIdx.x;
    unsigned short* srow = sc + row * 2048;
    const int tid = threadIdx.x;

    union { u16x4 p[2]; unsigned short u[8]; } in;
    in.p[0] = *(const u16x4*)(srow + tid * 8);
    in.p[1] = *(const u16x4*)(srow + tid * 8 + 4);
    float v[8];
#pragma unroll
    for (int i = 0; i < 8; ++i) v[i] = h2f(in.u[i]);

    float m = v[0];
#pragma unroll
    for (int i = 1; i < 8; ++i) m = fmaxf(m, v[i]);
#pragma unroll
    for (int off = 32; off; off >>= 1) m = fmaxf(m, __shfl_xor(m, off));

    __shared__ float redm[4], reds[4];
    if ((tid & 63) == 0) redm[tid >> 6] = m;
    __syncthreads();
    m = fmaxf(fmaxf(redm[0], redm[1]), fmaxf(redm[2], redm[3]));

    float s = 0.f;
#pragma unroll
    for (int i = 0; i < 8; ++i) { v[i] = __expf(v[i] - m); s += v[i]; }
#pragma unroll
    for (int off = 32; off; off >>= 1) s += __shfl_xor(s, off);
    if ((tid & 63) == 0) reds[tid >> 6] = s;
    __syncthreads();
    s = reds[0] + reds[1] + reds[2] + reds[3];

    const float inv = 1.f / s;
    union { unsigned short u[8]; f16x8 w; } t;
#pragma unroll
    for (int i = 0; i < 8; ++i) t.u[i] = f2h(v[i] * inv);
    *(f16x8*)(srow + tid * 8) = t.w;
}

extern "C" void kernel_launch(void* const* d_in, const int* in_sizes, int n_in,
                              void* d_out, int out_size, void* d_ws, size_t ws_size,
                              hipStream_t stream)
{
    const float* x  = (const float*)d_in[0];
    const float* wq = (const float*)d_in[1];
    const float* wk = (const float*)d_in[2];
    const float* wv = (const float*)d_in[3];
    float* out = (float*)d_out;

    // batched: [sc fp16 33.5MB (aliases xh 16.8 | wh 6.3)] [q][k][vt] = 83.9MB
    // looped:  [xh|wh 23.1MB (per-batch sc fp16 8.4MB aliases xh)][q][k][vt]
    //          = 73.4MB
    char* base = (char*)d_ws;
    const bool batched = (ws_size >= 88080384UL);   // 84 MB

    unsigned short* xh = (unsigned short*)base;
    unsigned short* wh = (unsigned short*)(base + 16777216);
    unsigned short* sc = (unsigned short*)base;
    unsigned short* q  = (unsigned short*)(base + (batched ? 33554432 : 23068672));
    unsigned short* k  = q + 8388608;
    unsigned short* vt = k + 8388608;

    // 0) conversions (single dispatch)
    cvt_all<<<5632, 256, 0, stream>>>(x, wq, wk, wv, xh, wh);

    // 1) z-merged projections: grid (64,8) = 512 blocks = 2 rounds at 2/CU
    proj3<<<dim3(64, 8), 256, 0, stream>>>(xh, wh, q, k, vt);

    if (batched) {
        // 2) scores fp16: M=N=2048 K=1024, z=batch; (8,16,4)=512 blocks
        gemm512<1, 128><<<dim3(8, 16, 4), 512, 0, stream>>>(
            q, k, sc, nullptr, 1024, 1024, 1024, 2048,
            2097152L, 2097152L, 4194304L);
        // 3) softmax in place (8192 rows, fp16->fp16)
        softmax16<<<8192, 256, 0, stream>>>(sc);
        // 4) out: M=2048 N=1024 K=2048; 256x64 tiles, (8,16,4)=512 blocks,
        //    double-buffered 2-phase (R9)
        gemm_out<<<dim3(8, 16, 4), 512, 0, stream>>>(
            sc, vt, out, 2048, 2048, 2048, 1024,
            4194304L, 2097152L, 2097152L);
    } else {
        for (int b = 0; b < 4; ++b) {
            gemm512<1, 128><<<dim3(8, 16, 1), 512, 0, stream>>>(
                q + (long)b * 2097152, k + (long)b * 2097152, sc, nullptr,
                1024, 1024, 1024, 2048, 0L, 0L, 0L);
            softmax16<<<2048, 256, 0, stream>>>(sc);
            gemm_out<<<dim3(8, 16, 1), 512, 0, stream>>>(
                sc, vt + (long)b * 2097152, out + (long)b * 2097152,
                2048, 2048, 2048, 1024, 0L, 0L, 0L);
        }
    }
}

// Round 5
// 227.914 us; speedup vs baseline: 1.0399x; 1.0399x over previous
//
#include <hip/hip_runtime.h>
#include <hip/hip_bf16.h>
#include <stdint.h>

// ---------------------------------------------------------------------------
// Self-attention, B=4 S=2048 D=1024, fp32 in/out, fp16 MFMA compute.
//   0) cvt: x -> xh fp16; w_q/w_k/w_v -> wh fp16 (one dispatch)
//   1) proj3 (R11): z-split-across-waves fused projection (q, k, vt).
//   2) scores = q_b @ k_b^T -> fp16 (z=batch)   [gemm512, R6-proven]
//   3) softmax rows in place fp16->fp16
//   4) out_b = attn_b @ vt_b^T (fp32)           [gemm_out R9-proven]
// proj3 v2: 768 thr = 12 waves = 3 z-groups x 4 waves. Each wave: one z,
// 64x64 quadrant of a 128x128 tile -> acc 16 f32x4 = 64 regs/wave (~150
// total) -> 3 waves/SIMD (R10's 320-reg/1-wave collapse fixed). A(x) tile
// staged ONCE per K-tile and shared by all 3 z (AI kept from R10: 384 MFMA
// per 64KB staged). BK=64 -> 16 tiles (half the barrier drains of R10).
// R9 skeleton: stage-ahead dbuf (2x64KB), ONE __syncthreads per K-tile.
// Grid (64,8)=512 = 2 rounds at 1 block/CU. MFMA order per output unchanged
// since R6 -> absmax canary 0.02539062.
// ---------------------------------------------------------------------------

typedef __attribute__((ext_vector_type(8))) _Float16 f16x8;
typedef __attribute__((ext_vector_type(4))) float f32x4;
typedef __attribute__((ext_vector_type(4))) unsigned short u16x4;

__device__ inline unsigned short f2h(float f) {
    union { _Float16 h; unsigned short u; } x;
    x.h = (_Float16)f;   // RNE
    return x.u;
}
__device__ inline float h2f(unsigned short u) {
    union { unsigned short u; _Float16 h; } x;
    x.u = u;
    return (float)x.h;
}

__device__ inline void async16(const unsigned short* g, unsigned short* l) {
    __builtin_amdgcn_global_load_lds(
        (__attribute__((address_space(1))) void*)g,
        (__attribute__((address_space(3))) void*)l, 16, 0, 0);
}

// ---------------------------------------------------------------------------
// proj3: x[8192][1024] fp16 @ {wq,wk,wv}^T -> q,k fp16 row-major + vt[b][d][s].
// LDS per 32768-half buffer: A[128][64] @0, B_z[128][64] @8192*(1+z).
// Staging: 16B chunk l of a 128x64 half-tile -> row r=l>>3, phys slot l&7
// holds logical k-chunk (l&7)^(r&7) (R6-proven XOR swizzle, 8-chunk rows).
// Waves: z = wave>>2 (0..2), wr = (wave>>1)&1, wc = wave&1.
// ---------------------------------------------------------------------------
__global__ __launch_bounds__(768, 3)
void proj3(const unsigned short* __restrict__ xh,
           const unsigned short* __restrict__ wh,
           unsigned short* __restrict__ q,
           unsigned short* __restrict__ kk,
           unsigned short* __restrict__ vt)
{
    __shared__ __align__(16) unsigned short smem[2 * 32768];   // 128 KB

    const int tid  = threadIdx.x;
    const int lane = tid & 63;
    const int wave = tid >> 6;          // 0..11
    const int z    = wave >> 2;         // 0..2
    const int wr   = (wave >> 1) & 1;   // 64-row band
    const int wc   = wave & 1;          // 64-col band
    const int quad = lane >> 4, lrow = lane & 15;
    const int bm   = blockIdx.x, bn = blockIdx.y;   // bm fastest (share W in L2)

    // A staging: 1024 chunks; threads 0..511 stage 2 each (l = tid, tid+512).
    const unsigned short* gA0 = nullptr;
    const unsigned short* gA1 = nullptr;
    if (tid < 512) {
#pragma unroll
        for (int i = 0; i < 2; ++i) {
            const int l = tid + 512 * i;
            const int r = l >> 3;
            const int c = (l & 7) ^ (r & 7);
            const unsigned short* p =
                xh + (long)(bm * 128 + r) * 1024 + c * 8;
            if (i == 0) gA0 = p; else gA1 = p;
        }
    }
    // B staging: 3 x 1024 chunks; all 768 threads stage 4 (b = tid + 768*i).
    // b never crosses a z (1024-chunk) boundary within a wave (64 | 768,1024).
    const unsigned short* gB[4];
    int dB[4];
#pragma unroll
    for (int i = 0; i < 4; ++i) {
        const int b  = tid + 768 * i;
        const int bz = b >> 10;
        const int l  = b & 1023;
        const int r  = l >> 3;
        const int c  = (l & 7) ^ (r & 7);
        gB[i] = wh + (long)bz * 1048576 + (long)(bn * 128 + r) * 1024 + c * 8;
        dB[i] = 8192 * (1 + bz) + l * 8;
    }

    f32x4 acc[4][4];
#pragma unroll
    for (int m = 0; m < 4; ++m)
#pragma unroll
        for (int n = 0; n < 4; ++n)
            acc[m][n] = f32x4{0.f, 0.f, 0.f, 0.f};

    const int fr = lrow & 7;   // row bits for fragment de-swizzle
    const int zofs = 8192 * (1 + z);

    // ---- prologue: tile 0 -> buf0 ----
    if (tid < 512) {
        async16(gA0, &smem[tid * 8]);
        async16(gA1, &smem[(tid + 512) * 8]);
        gA0 += 64; gA1 += 64;
    }
#pragma unroll
    for (int i = 0; i < 4; ++i) {
        async16(gB[i], &smem[dB[i]]);
        gB[i] += 64;
    }
    __syncthreads();   // implicit vmcnt(0): tile0 visible

    for (int t = 0; t < 16; ++t) {
        const unsigned short* cb = smem + (t & 1) * 32768;

        // stage tile t+1 into the other buffer (dead since barrier t-1);
        // HBM/L2 latency hides under this tile's ds_reads + 32 MFMA.
        if (t + 1 < 16) {
            unsigned short* nb = smem + ((t + 1) & 1) * 32768;
            if (tid < 512) {
                async16(gA0, &nb[tid * 8]);
                async16(gA1, &nb[(tid + 512) * 8]);
                gA0 += 64; gA1 += 64;
            }
#pragma unroll
            for (int i = 0; i < 4; ++i) {
                async16(gB[i], &nb[dB[i]]);
                gB[i] += 64;
            }
        }

#pragma unroll
        for (int ks = 0; ks < 2; ++ks) {
            const int pc = (((ks << 2) + quad) ^ fr) * 8;
            f16x8 af[4], bf[4];
#pragma unroll
            for (int mt = 0; mt < 4; ++mt)
                af[mt] = *(const f16x8*)&cb[(wr * 64 + mt * 16 + lrow) * 64 + pc];
#pragma unroll
            for (int nt = 0; nt < 4; ++nt)
                bf[nt] = *(const f16x8*)
                    &cb[zofs + (wc * 64 + nt * 16 + lrow) * 64 + pc];
#pragma unroll
            for (int mt = 0; mt < 4; ++mt)
#pragma unroll
                for (int nt = 0; nt < 4; ++nt)
                    acc[mt][nt] = __builtin_amdgcn_mfma_f32_16x16x32_f16(
                        af[mt], bf[nt], acc[mt][nt], 0, 0, 0);
        }

        if (t + 1 < 16)
            __syncthreads();   // drain(t+1 loads) + all waves done with cb
    }

    // ---- epilogue: q, k row-major fp16 (z<2 waves) ----
    if (z < 2) {
        unsigned short* dst = z ? kk : q;
#pragma unroll
        for (int mt = 0; mt < 4; ++mt)
#pragma unroll
            for (int nt = 0; nt < 4; ++nt)
#pragma unroll
                for (int r = 0; r < 4; ++r) {
                    const int row = bm * 128 + wr * 64 + mt * 16 + quad * 4 + r;
                    const int col = bn * 128 + wc * 64 + nt * 16 + lrow;
                    dst[(long)row * 1024 + col] = f2h(acc[mt][nt][r]);
                }
    }

    // ---- epilogue: vt transpose (2 bands of 64 token-rows, z==2 waves) ----
    // T[col 128][row 64] pitch 72 halves; aliases smem buf0 (dead: its last
    // tile (14) was fully read before the barrier at end of t=14).
    unsigned short* T = smem;   // 128*72 = 9216 halves
#pragma unroll
    for (int p = 0; p < 2; ++p) {
        __syncthreads();
        if (z == 2 && wr == p) {
#pragma unroll
            for (int mt = 0; mt < 4; ++mt)
#pragma unroll
                for (int nt = 0; nt < 4; ++nt) {
                    const int row_l = mt * 16 + quad * 4;
                    const int col_l = wc * 64 + nt * 16 + lrow;
                    u16x4 pk = {f2h(acc[mt][nt][0]), f2h(acc[mt][nt][1]),
                                f2h(acc[mt][nt][2]), f2h(acc[mt][nt][3])};
                    *(u16x4*)&T[col_l * 72 + row_l] = pk;
                }
        }
        __syncthreads();
        // copy out: 128 cols x 64 rows = 8192 halves = 512 thr x 16
        if (tid < 512) {
            const int c  = tid >> 2;
            const int j0 = (tid & 3) * 16;
            const int tok0 = bm * 128 + p * 64;   // tile never crosses a batch
            const int bb = tok0 >> 11;            // (2048 % 128 == 0)
            const int s0 = (tok0 & 2047) + j0;
            unsigned short* dst = vt + (long)bb * 2097152 +
                                  (long)(bn * 128 + c) * 2048 + s0;
            const unsigned short* srcT = &T[c * 72 + j0];
            *(f16x8*)dst       = *(const f16x8*)srcT;
            *(f16x8*)(dst + 8) = *(const f16x8*)(srcT + 8);
        }
    }
}

// MODE 1: fp16 row-major into C (scores). Tile: BM=256 x BN, BK=64.
// 8 waves: wr=wave>>1 (4), wc=wave&1 (2). Serial stage->drain->compute,
// 48 KB LDS, 3 blocks/CU (best measured structure for this K).
template <int MODE, int BN>
__global__ __launch_bounds__(512)
void gemm512(const unsigned short* __restrict__ A,
             const unsigned short* __restrict__ B,
             void* __restrict__ C, void* __restrict__ C2,
             int K, int ldA, int ldB, int ldC,
             long sAz, long sBz, long sCz)
{
    constexpr int NT = BN / 32;           // MFMA col-tiles per wave
    constexpr int BI = BN / 64;           // B staging chunks per thread
    __shared__ __align__(16) unsigned short smem[256 * 64 + BN * 64];
    unsigned short* As = smem;
    unsigned short* Bs = smem + 256 * 64;

    const int tid  = threadIdx.x;
    const int lane = tid & 63;
    const int wave = tid >> 6;
    const int wr   = wave >> 1, wc = wave & 1;
    const int quad = lane >> 4, lrow = lane & 15;
    const int bm   = blockIdx.x, bn = blockIdx.y, z = blockIdx.z;  // bm fastest

    const unsigned short* Az = A + (long)z * sAz;
    const unsigned short* Bz = B + (long)z * sBz;

    const unsigned short* gA[4];
    const unsigned short* gB[BI];
#pragma unroll
    for (int i = 0; i < 4; ++i) {
        const int l = tid + 512 * i;
        const int r = l >> 3;
        const int c = (l & 7) ^ (r & 7);
        gA[i] = Az + (long)(bm * 256 + r) * ldA + c * 8;
    }
#pragma unroll
    for (int i = 0; i < BI; ++i) {
        const int l = tid + 512 * i;
        const int r = l >> 3;
        const int c = (l & 7) ^ (r & 7);
        gB[i] = Bz + (long)(bn * BN + r) * ldB + c * 8;
    }

    f32x4 acc[4][NT];
#pragma unroll
    for (int i = 0; i < 4; ++i)
#pragma unroll
        for (int j = 0; j < NT; ++j)
            acc[i][j] = f32x4{0.f, 0.f, 0.f, 0.f};

    const int fr = lrow & 7;   // row bits for fragment de-swizzle

    for (int k0 = 0; k0 < K; k0 += 64) {
#pragma unroll
        for (int i = 0; i < 4; ++i) async16(gA[i], &As[(tid + 512 * i) * 8]);
#pragma unroll
        for (int i = 0; i < BI; ++i) async16(gB[i], &Bs[(tid + 512 * i) * 8]);
#pragma unroll
        for (int i = 0; i < 4; ++i) gA[i] += 64;
#pragma unroll
        for (int i = 0; i < BI; ++i) gB[i] += 64;
        __syncthreads();   // drains vmcnt -> tiles visible

#pragma unroll
        for (int ks = 0; ks < 2; ++ks) {
            const int pc = (((ks << 2) + quad) ^ fr) * 8;
            f16x8 af[4], bf[NT];
#pragma unroll
            for (int mt = 0; mt < 4; ++mt)
                af[mt] = *(const f16x8*)&As[(wr * 64 + mt * 16 + lrow) * 64 + pc];
#pragma unroll
            for (int nt = 0; nt < NT; ++nt)
                bf[nt] = *(const f16x8*)&Bs[(wc * (BN / 2) + nt * 16 + lrow) * 64 + pc];
#pragma unroll
            for (int mt = 0; mt < 4; ++mt)
#pragma unroll
                for (int nt = 0; nt < NT; ++nt)
                    acc[mt][nt] = __builtin_amdgcn_mfma_f32_16x16x32_f16(
                        af[mt], bf[nt], acc[mt][nt], 0, 0, 0);
        }
        __syncthreads();   // LDS reusable
    }

    const int col_base = bn * BN + wc * (BN / 2);
    const int row_base = bm * 256 + wr * 64;
    const long zC = (long)z * sCz;
#pragma unroll
    for (int mt = 0; mt < 4; ++mt)
#pragma unroll
        for (int nt = 0; nt < NT; ++nt)
#pragma unroll
            for (int r = 0; r < 4; ++r) {
                const int row = row_base + mt * 16 + quad * 4 + r;
                const int col = col_base + nt * 16 + lrow;
                if (MODE == 2)
                    ((float*)C)[zC + (long)row * ldC + col] = acc[mt][nt][r];
                else
                    ((unsigned short*)C)[zC + (long)row * ldC + col] =
                        f2h(acc[mt][nt][r]);
            }
}

// R9 out GEMM. BM=256 x BN=64, BK=64, fp32 row-major C. Double-buffered
// 2-phase: stage(t+1) issued BEFORE compute(t); ONE __syncthreads per K-tile.
// LDS 2 x 40 KB = 80 KB -> 2 blocks/CU (matches 512-block grid).
__global__ __launch_bounds__(512)
void gemm_out(const unsigned short* __restrict__ A,
              const unsigned short* __restrict__ B,
              float* __restrict__ C,
              int K, int ldA, int ldB, int ldC,
              long sAz, long sBz, long sCz)
{
    constexpr int TILE_H = 256 * 64 + 64 * 64;   // 20480 halves = 40 KB
    __shared__ __align__(16) unsigned short smem[2 * TILE_H];

    const int tid  = threadIdx.x;
    const int lane = tid & 63;
    const int wave = tid >> 6;
    const int wr   = wave >> 1, wc = wave & 1;
    const int quad = lane >> 4, lrow = lane & 15;
    const int bm   = blockIdx.x, bn = blockIdx.y, z = blockIdx.z;  // bm fastest

    const unsigned short* Az = A + (long)z * sAz;
    const unsigned short* Bz = B + (long)z * sBz;

    const unsigned short* gA[4];
    const unsigned short* gB1;
#pragma unroll
    for (int i = 0; i < 4; ++i) {
        const int l = tid + 512 * i;
        const int r = l >> 3;
        const int c = (l & 7) ^ (r & 7);
        gA[i] = Az + (long)(bm * 256 + r) * ldA + c * 8;
    }
    {
        const int r = tid >> 3;
        const int c = (tid & 7) ^ (r & 7);
        gB1 = Bz + (long)(bn * 64 + r) * ldB + c * 8;
    }

    f32x4 acc[4][2];
#pragma unroll
    for (int i = 0; i < 4; ++i)
#pragma unroll
        for (int j = 0; j < 2; ++j)
            acc[i][j] = f32x4{0.f, 0.f, 0.f, 0.f};

    const int fr = lrow & 7;
    const int ntiles = K >> 6;

    // prologue: stage tile0 into buf0
#pragma unroll
    for (int i = 0; i < 4; ++i) async16(gA[i], &smem[(tid + 512 * i) * 8]);
    async16(gB1, &smem[256 * 64 + tid * 8]);
#pragma unroll
    for (int i = 0; i < 4; ++i) gA[i] += 64;
    gB1 += 64;
    __syncthreads();   // drains vmcnt(0): tile0 visible

    for (int t = 0; t < ntiles; ++t) {
        const unsigned short* As = smem + (t & 1) * TILE_H;
        const unsigned short* Bs = As + 256 * 64;

        if (t + 1 < ntiles) {
            unsigned short* nA = smem + ((t + 1) & 1) * TILE_H;
#pragma unroll
            for (int i = 0; i < 4; ++i) {
                async16(gA[i], &nA[(tid + 512 * i) * 8]);
                gA[i] += 64;
            }
            async16(gB1, &nA[256 * 64 + tid * 8]);
            gB1 += 64;
        }

#pragma unroll
        for (int ks = 0; ks < 2; ++ks) {
            const int pc = (((ks << 2) + quad) ^ fr) * 8;
            f16x8 af[4], bf[2];
#pragma unroll
            for (int mt = 0; mt < 4; ++mt)
                af[mt] = *(const f16x8*)&As[(wr * 64 + mt * 16 + lrow) * 64 + pc];
#pragma unroll
            for (int nt = 0; nt < 2; ++nt)
                bf[nt] = *(const f16x8*)&Bs[(wc * 32 + nt * 16 + lrow) * 64 + pc];
#pragma unroll
            for (int mt = 0; mt < 4; ++mt)
#pragma unroll
                for (int nt = 0; nt < 2; ++nt)
                    acc[mt][nt] = __builtin_amdgcn_mfma_f32_16x16x32_f16(
                        af[mt], bf[nt], acc[mt][nt], 0, 0, 0);
        }

        if (t + 1 < ntiles)
            __syncthreads();   // drain(t+1 loads) + all waves done reading buf
    }

    const int col_base = bn * 64 + wc * 32;
    const int row_base = bm * 256 + wr * 64;
    const long zC = (long)z * sCz;
#pragma unroll
    for (int mt = 0; mt < 4; ++mt)
#pragma unroll
        for (int nt = 0; nt < 2; ++nt)
#pragma unroll
            for (int r = 0; r < 4; ++r) {
                const int row = row_base + mt * 16 + quad * 4 + r;
                const int col = col_base + nt * 16 + lrow;
                C[zC + (long)row * ldC + col] = acc[mt][nt][r];
            }
}

// fused fp32 -> fp16 conversion: blocks [0,4096) -> x, [4096,5632) -> weights
__global__ __launch_bounds__(256)
void cvt_all(const float* __restrict__ x, const float* __restrict__ w0,
             const float* __restrict__ w1, const float* __restrict__ w2,
             unsigned short* __restrict__ xh, unsigned short* __restrict__ wh)
{
    const int bid = blockIdx.x;
    const float* s;
    unsigned short* d;
    long i;
    if (bid < 4096) {
        s = x; d = xh;
        i = ((long)bid * 256 + threadIdx.x) * 8;
    } else {
        const int wid = bid - 4096;          // [0,1536)
        const int w = wid >> 9;              // weight index
        s = (w == 0) ? w0 : (w == 1) ? w1 : w2;
        d = wh + (long)w * 1048576;
        i = ((long)(wid & 511) * 256 + threadIdx.x) * 8;
    }
    f32x4 a = *(const f32x4*)(s + i);
    f32x4 b = *(const f32x4*)(s + i + 4);
    union { unsigned short u[8]; f16x8 v; } t;
#pragma unroll
    for (int j = 0; j < 4; ++j) { t.u[j] = f2h(a[j]); t.u[4 + j] = f2h(b[j]); }
    *(f16x8*)(d + i) = t.v;
}

// in-place fp16 row softmax: row = 2048 fp16, one block per row.
__global__ __launch_bounds__(256)
void softmax16(unsigned short* __restrict__ sc)
{
    const long row = blockIdx.x;
    unsigned short* srow = sc + row * 2048;
    const int tid = threadIdx.x;

    union { u16x4 p[2]; unsigned short u[8]; } in;
    in.p[0] = *(const u16x4*)(srow + tid * 8);
    in.p[1] = *(const u16x4*)(srow + tid * 8 + 4);
    float v[8];
#pragma unroll
    for (int i = 0; i < 8; ++i) v[i] = h2f(in.u[i]);

    float m = v[0];
#pragma unroll
    for (int i = 1; i < 8; ++i) m = fmaxf(m, v[i]);
#pragma unroll
    for (int off = 32; off; off >>= 1) m = fmaxf(m, __shfl_xor(m, off));

    __shared__ float redm[4], reds[4];
    if ((tid & 63) == 0) redm[tid >> 6] = m;
    __syncthreads();
    m = fmaxf(fmaxf(redm[0], redm[1]), fmaxf(redm[2], redm[3]));

    float s = 0.f;
#pragma unroll
    for (int i = 0; i < 8; ++i) { v[i] = __expf(v[i] - m); s += v[i]; }
#pragma unroll
    for (int off = 32; off; off >>= 1) s += __shfl_xor(s, off);
    if ((tid & 63) == 0) reds[tid >> 6] = s;
    __syncthreads();
    s = reds[0] + reds[1] + reds[2] + reds[3];

    const float inv = 1.f / s;
    union { unsigned short u[8]; f16x8 w; } t;
#pragma unroll
    for (int i = 0; i < 8; ++i) t.u[i] = f2h(v[i] * inv);
    *(f16x8*)(srow + tid * 8) = t.w;
}

extern "C" void kernel_launch(void* const* d_in, const int* in_sizes, int n_in,
                              void* d_out, int out_size, void* d_ws, size_t ws_size,
                              hipStream_t stream)
{
    const float* x  = (const float*)d_in[0];
    const float* wq = (const float*)d_in[1];
    const float* wk = (const float*)d_in[2];
    const float* wv = (const float*)d_in[3];
    float* out = (float*)d_out;

    // batched: [sc fp16 33.5MB (aliases xh 16.8 | wh 6.3)] [q][k][vt] = 83.9MB
    // looped:  [xh|wh 23.1MB (per-batch sc fp16 8.4MB aliases xh)][q][k][vt]
    //          = 73.4MB
    char* base = (char*)d_ws;
    const bool batched = (ws_size >= 88080384UL);   // 84 MB

    unsigned short* xh = (unsigned short*)base;
    unsigned short* wh = (unsigned short*)(base + 16777216);
    unsigned short* sc = (unsigned short*)base;
    unsigned short* q  = (unsigned short*)(base + (batched ? 33554432 : 23068672));
    unsigned short* k  = q + 8388608;
    unsigned short* vt = k + 8388608;

    // 0) conversions (single dispatch)
    cvt_all<<<5632, 256, 0, stream>>>(x, wq, wk, wv, xh, wh);

    // 1) z-split fused projections: grid (64,8) = 512 blocks = 2 rounds
    proj3<<<dim3(64, 8), 768, 0, stream>>>(xh, wh, q, k, vt);

    if (batched) {
        // 2) scores fp16: M=N=2048 K=1024, z=batch; (8,16,4)=512 blocks
        gemm512<1, 128><<<dim3(8, 16, 4), 512, 0, stream>>>(
            q, k, sc, nullptr, 1024, 1024, 1024, 2048,
            2097152L, 2097152L, 4194304L);
        // 3) softmax in place (8192 rows, fp16->fp16)
        softmax16<<<8192, 256, 0, stream>>>(sc);
        // 4) out: M=2048 N=1024 K=2048; 256x64 tiles, (8,16,4)=512 blocks,
        //    double-buffered 2-phase (R9)
        gemm_out<<<dim3(8, 16, 4), 512, 0, stream>>>(
            sc, vt, out, 2048, 2048, 2048, 1024,
            4194304L, 2097152L, 2097152L);
    } else {
        for (int b = 0; b < 4; ++b) {
            gemm512<1, 128><<<dim3(8, 16, 1), 512, 0, stream>>>(
                q + (long)b * 2097152, k + (long)b * 2097152, sc, nullptr,
                1024, 1024, 1024, 2048, 0L, 0L, 0L);
            softmax16<<<2048, 256, 0, stream>>>(sc);
            gemm_out<<<dim3(8, 16, 1), 512, 0, stream>>>(
                sc, vt + (long)b * 2097152, out + (long)b * 2097152,
                2048, 2048, 2048, 1024, 0L, 0L, 0L);
        }
    }
}